// Round 8
// baseline (3487.325 us; speedup 1.0000x reference)
//
#include <hip/hip_runtime.h>
#include <cstdint>
#include <cstddef>

// ---------------------------------------------------------------------------
// QRNN 2-bit forward, exact ternary-integer formulation.
// flags[0]=1 -> floats are f32 (else bf16); flags[1]=1 -> text is int64.
// Ternary vectors (len 1024) bit-packed as 32 u64: [2i]=plus, [2i+1]=nonzero.
// As uint4 i: (p.lo, p.hi, z.lo, z.hi) for elements 64i..64i+63.
// dot: both=hz&wz; neg=both&(hp^wp); k=popc(both)-2*popc(neg)
// Decision v = k*0.1+bias vs +-0.5 is monotone in k -> integer thresholds
// kp/km reproduce the f64 predicate bit-exactly.
//
// R8 k_recur: DELTA recurrence. S = dot(h(t-1), w) maintained incrementally:
// only h-words changed between steps contribute (3-deep LDS h-history +
// 16-byte changed bitmap; single barrier/step). h converges to a fixed point
// within a few steps (R6/R7 counters), so steady-state steps do NO dot work
// for any block. nbuf transposed to [b][r][t] so nin is one uint4 per thread
// per 8 steps (no per-step vmem drain at the barrier).
// ---------------------------------------------------------------------------

static __device__ __forceinline__ float bf2f(unsigned short b) {
  return __uint_as_float(((unsigned)b) << 16);
}
static __device__ __forceinline__ unsigned short f2bf(float f) {
  unsigned u = __float_as_uint(f);
  u = (u + 0x7FFFu + ((u >> 16) & 1u)) >> 16;  // RNE
  return (unsigned short)u;
}
static __device__ __forceinline__ float loadw(const void* p, size_t i, int isf32) {
  return isf32 ? ((const float*)p)[i] : bf2f(((const unsigned short*)p)[i]);
}

__global__ __launch_bounds__(256) void k_detect(const unsigned short* __restrict__ embu,
                                                const int* __restrict__ text,
                                                int* __restrict__ flags) {
  int i = blockIdx.x * 256 + threadIdx.x;  // 65536 u16 samples: valid in either layout
  unsigned e = (embu[i] >> 7) & 0xFFu;     // bf16-view exponent field
  unsigned long long b = __ballot(e >= 127u);
  if ((threadIdx.x & 63) == 0 && b) atomicOr(&flags[0], 1);
  if (blockIdx.x == 0 && threadIdx.x == 0) {
    int allz = 1;
    for (int j = 0; j < 32; j++)
      if (text[2 * j + 1] != 0) allz = 0;   // first 256 B: valid in either layout
    flags[1] = allz;
  }
}

__global__ __launch_bounds__(256) void k_maxabs(const uint4* __restrict__ w,
                                                const int* __restrict__ flags,
                                                unsigned* __restrict__ out) {
  int isf32 = flags[0];
  int n16 = isf32 ? 7680000 : 3840000;  // 30720000 elems / (4 or 8 per uint4)
  float mf = 0.f;
  unsigned mb = 0;
  int i = blockIdx.x * blockDim.x + threadIdx.x;
  int stride = gridDim.x * blockDim.x;
  if (isf32) {
    for (; i < n16; i += stride) {
      uint4 v = w[i];
      mf = fmaxf(mf, fabsf(__uint_as_float(v.x)));
      mf = fmaxf(mf, fabsf(__uint_as_float(v.y)));
      mf = fmaxf(mf, fabsf(__uint_as_float(v.z)));
      mf = fmaxf(mf, fabsf(__uint_as_float(v.w)));
    }
  } else {
    for (; i < n16; i += stride) {
      uint4 v = w[i];
      unsigned a;
      a = v.x & 0x7FFF7FFFu; mb = max(mb, a & 0xFFFFu); mb = max(mb, a >> 16);
      a = v.y & 0x7FFF7FFFu; mb = max(mb, a & 0xFFFFu); mb = max(mb, a >> 16);
      a = v.z & 0x7FFF7FFFu; mb = max(mb, a & 0xFFFFu); mb = max(mb, a >> 16);
      a = v.w & 0x7FFF7FFFu; mb = max(mb, a & 0xFFFFu); mb = max(mb, a >> 16);
    }
    mf = bf2f((unsigned short)mb);
  }
  for (int off = 32; off > 0; off >>= 1) mf = fmaxf(mf, __shfl_down(mf, off));
  __shared__ float red[4];
  if ((threadIdx.x & 63) == 0) red[threadIdx.x >> 6] = mf;
  __syncthreads();
  if (threadIdx.x == 0) {
    float b = fmaxf(fmaxf(red[0], red[1]), fmaxf(red[2], red[3]));
    atomicMax(out, __float_as_uint(b));  // b >= 0: bit pattern order-monotone
  }
}

__global__ __launch_bounds__(1024) void k_tern_rows(
    const void* __restrict__ Wih, const void* __restrict__ Whh,
    const void* __restrict__ fcw, const int* __restrict__ flags,
    unsigned long long* __restrict__ wim, unsigned long long* __restrict__ whm,
    unsigned long long* __restrict__ fcm) {
  int isf32 = flags[0];
  int b = blockIdx.x;  // 0..4099
  const void* src;
  size_t rowoff;
  unsigned long long* dst;
  if (b < 2048)      { src = Wih; rowoff = (size_t)b * 1024; dst = wim + (size_t)b * 32; }
  else if (b < 4096) { int r = b - 2048; src = Whh; rowoff = (size_t)r * 1024; dst = whm + (size_t)r * 32; }
  else               { int r = b - 4096; src = fcw; rowoff = (size_t)r * 1024; dst = fcm + (size_t)r * 32; }
  double w = (double)loadw(src, rowoff + threadIdx.x, isf32);
  unsigned long long bp = __ballot(w > 0.05);   // THR*W_SCALE, exact f64
  unsigned long long bm = __ballot(w < -0.05);
  if ((threadIdx.x & 63) == 0) {
    int wv = threadIdx.x >> 6;
    dst[2 * wv] = bp;
    dst[2 * wv + 1] = bp | bm;
  }
}

__global__ __launch_bounds__(1024) void k_embed(const int* __restrict__ text,
    const void* __restrict__ emb, const int* __restrict__ flags,
    const unsigned* __restrict__ mab, unsigned long long* __restrict__ x0) {
  int isf32 = flags[0], i64 = flags[1];
  int bt = blockIdx.x;
  long long tok = i64 ? ((const long long*)text)[bt] : (long long)text[bt];
  double ma = (double)__uint_as_float(*mab);
  float s = (float)exp2(ceil(log2(ma)));           // pow-2 scale (int_max = 1)
  float inv_s = 1.0f / s;                          // exact (pow-2)
  float w = loadw(emb, (size_t)tok * 1024 + threadIdx.x, isf32);
  float q = rintf(w * inv_s);                      // exact mul, half-even
  q = fminf(fmaxf(q, -2.0f), 1.0f);                // clip [-2, 1] (bw = 2)
  float val = q * s;                               // exact
  int code = (val > 0.5f) ? 1 : ((val < -0.5f) ? -1 : 0);
  unsigned long long bp = __ballot(code == 1);
  unsigned long long bm = __ballot(code == -1);
  if ((threadIdx.x & 63) == 0) {
    int wv = threadIdx.x >> 6;
    x0[(size_t)bt * 32 + 2 * wv] = bp;
    x0[(size_t)bt * 32 + 2 * wv + 1] = bp | bm;
  }
}

// ---- bit-GEMM: nT[b][r][t] = <x_row[b,t], Wi_row[r]> (integer) ------------
// Output TRANSPOSED to [b][r][t] so k_recur reads 8 steps per uint4.
__global__ __launch_bounds__(256, 4) void k_bitgemm(const unsigned long long* __restrict__ xm,
    const unsigned long long* __restrict__ wim, short* __restrict__ nbufT) {
  __shared__ __align__(16) uint4 lx[64 * 16];  // [bt][i] = (p.lo,p.hi,z.lo,z.hi)
  __shared__ unsigned any[64];
  int tid = threadIdx.x;
  int bt0 = blockIdx.x * 64;           // 64 consecutive t of one batch b
  int b = bt0 >> 9, t0 = bt0 & 511;
  int r = blockIdx.y * 256 + tid;
  unsigned wplo[16], wphi[16], wzlo[16], wzhi[16];
  const uint4* wrow = (const uint4*)(wim + (size_t)r * 32);
#pragma unroll
  for (int i = 0; i < 16; i++) {
    uint4 w4 = wrow[i];
    wplo[i] = w4.x; wphi[i] = w4.y; wzlo[i] = w4.z; wzhi[i] = w4.w;
  }
  if (tid < 64) any[tid] = 0;
  __syncthreads();
  unsigned accor = 0;
#pragma unroll
  for (int i = 0; i < 4; i++) {
    int idx = tid * 4 + i;  // 0..1023 uint4 slots, straight copy
    uint4 v = ((const uint4*)(xm + (size_t)bt0 * 32))[idx];
    lx[idx] = v;
    accor |= v.z | v.w;  // nonzero-mask halves
  }
  if (accor) atomicOr(&any[tid >> 2], 1u);  // 4 threads per bt row
  __syncthreads();
  uint4* orow = (uint4*)(nbufT) + ((size_t)b * 1024 + r) * 64 + (t0 >> 3);
  for (int g = 0; g < 8; g++) {
    unsigned pk[4];
#pragma unroll
    for (int q = 0; q < 8; q++) {
      int bt = g * 8 + q;
      int k = 0;
      if (any[bt]) {
        const uint4* hx = lx + bt * 16;
        int sb = 0, sn = 0;
#pragma unroll
        for (int i = 0; i < 16; i++) {
          uint4 h = hx[i];  // broadcast ds_read_b128, batched
          unsigned blo = h.z & wzlo[i];
          unsigned bhi = h.w & wzhi[i];
          unsigned nlo = (h.x ^ wplo[i]) & blo;
          unsigned nhi = (h.y ^ wphi[i]) & bhi;
          sb += __popc(blo) + __popc(bhi);
          sn += __popc(nlo) + __popc(nhi);
        }
        k = sb - 2 * sn;
      }
      unsigned ks = (unsigned)(unsigned short)(short)k;
      if ((q & 1) == 0) pk[q >> 1] = ks;
      else pk[q >> 1] |= ks << 16;
    }
    uint4 o; o.x = pk[0]; o.y = pk[1]; o.z = pk[2]; o.w = pk[3];
    orow[g] = o;
  }
}

// ---- delta persistent recurrence (single CU per batch) --------------------
// 1024 threads, thread = output row. S = dot(h(t-1), w_row) kept incrementally
// via 3-deep h history + changed-word bitmap. Steady state: no dot work.
__global__ __launch_bounds__(1024, 4) void k_recur(const short* __restrict__ nbufT,
    const unsigned long long* __restrict__ whm,
    const void* __restrict__ bih, const void* __restrict__ bhh,
    const int* __restrict__ flags, int layer,
    unsigned long long* __restrict__ xout, unsigned long long* __restrict__ hidm) {
  int isf32 = flags[0];
  int b = blockIdx.x, r = threadIdx.x;
  int wv = r >> 6, lane = r & 63;
  unsigned wplo[16], wphi[16], wzlo[16], wzhi[16];
  const uint4* wrow = (const uint4*)(whm + (size_t)r * 32);
#pragma unroll
  for (int i = 0; i < 16; i++) {
    uint4 w4 = wrow[i];
    wplo[i] = w4.x; wphi[i] = w4.y; wzlo[i] = w4.z; wzhi[i] = w4.w;
  }
  size_t boff = (size_t)layer * 1024 + r;
  double bias = (double)loadw(bih, boff, isf32) + (double)loadw(bhh, boff, isf32);
  int kp = (int)ceil((0.5 - bias) * 10.0);
  while ((double)kp * 0.1 + bias <= 0.5) kp++;
  while ((double)(kp - 1) * 0.1 + bias > 0.5) kp--;
  int km = (int)floor((-0.5 - bias) * 10.0);
  while ((double)km * 0.1 + bias >= -0.5) km--;
  while ((double)(km + 1) * 0.1 + bias < -0.5) km++;

  __shared__ __align__(16) uint4 Hbuf[3][16];  // h history ring
  __shared__ __align__(16) uint4 cbuf[3];      // byte i = (word i changed)
  if (r < 96) ((unsigned*)Hbuf)[r * 4 % 384] = 0;  // (overwritten below properly)
  if (r < 48) ((unsigned*)Hbuf)[r] = 0;
  if (r < 96) { ((unsigned*)Hbuf)[r] = 0; }
  if (r < 192) ((unsigned*)Hbuf)[r] = 0;           // zero all 3*16*4 = 192 u32
  if (r < 12) ((unsigned*)cbuf)[r] = 0;
  __syncthreads();

  const uint4* nb4 = (const uint4*)(nbufT) + ((size_t)b * 1024 + r) * 64;
  unsigned long long* xrow = xout ? xout + (size_t)b * 512 * 32 : (unsigned long long*)0;
  uint4 cur = nb4[0];
  int S = 0;
  int pb = 0;  // Hbuf[pb] = h(t-1); Hbuf[(pb+2)%3] = h(t-2); write to (pb+1)%3
  uint4 op; op.x = 0; op.y = 0; op.z = 0; op.w = 0;  // lane0: previous o
  for (int tb = 0; tb < 64; tb++) {
    uint4 nxt;
    if (tb < 63) nxt = nb4[tb + 1];  // prefetch next 8 steps' nin
#pragma unroll
    for (int ph = 0; ph < 8; ph++) {
      int t = tb * 8 + ph;
      int pm = (pb == 0) ? 2 : pb - 1;   // h(t-2)
      int nx = (pb == 2) ? 0 : pb + 1;   // write target (holds dead h(t-3))
      // --- delta-S update from words changed h(t-2) -> h(t-1) ---
      uint4 cbv = cbuf[pb];
      unsigned m0 = (unsigned)__builtin_amdgcn_readfirstlane((int)cbv.x);
      unsigned m1 = (unsigned)__builtin_amdgcn_readfirstlane((int)cbv.y);
      unsigned m2 = (unsigned)__builtin_amdgcn_readfirstlane((int)cbv.z);
      unsigned m3 = (unsigned)__builtin_amdgcn_readfirstlane((int)cbv.w);
      if (m0 | m1 | m2 | m3) {  // block-uniform; rare after convergence
#pragma unroll
        for (int i = 0; i < 16; i++) {
          unsigned mw = (i < 4) ? m0 : (i < 8) ? m1 : (i < 12) ? m2 : m3;
          if ((mw >> (8 * (i & 3))) & 0xFFu) {
            uint4 hn = Hbuf[pb][i];
            uint4 ho = Hbuf[pm][i];
            unsigned blo, bhi, nlo, nhi;
            blo = hn.z & wzlo[i]; bhi = hn.w & wzhi[i];
            nlo = (hn.x ^ wplo[i]) & blo; nhi = (hn.y ^ wphi[i]) & bhi;
            S += __popc(blo) + __popc(bhi) - 2 * (__popc(nlo) + __popc(nhi));
            blo = ho.z & wzlo[i]; bhi = ho.w & wzhi[i];
            nlo = (ho.x ^ wplo[i]) & blo; nhi = (ho.y ^ wphi[i]) & bhi;
            S -= __popc(blo) + __popc(bhi) - 2 * (__popc(nlo) + __popc(nhi));
          }
        }
      }
      // --- decision ---
      unsigned wsel = (ph < 2) ? cur.x : (ph < 4) ? cur.y : (ph < 6) ? cur.z : cur.w;
      int nin = (int)(short)((ph & 1) ? (wsel >> 16) : (wsel & 0xFFFFu));
      int k = nin + S;
      unsigned long long bp = __ballot(k >= kp);
      unsigned long long bz = bp | __ballot(k <= km);
      if (lane == 0) {
        uint4 o;
        o.x = (unsigned)bp; o.y = (unsigned)(bp >> 32);
        o.z = (unsigned)bz; o.w = (unsigned)(bz >> 32);
        Hbuf[nx][wv] = o;
        unsigned ch = (o.x ^ op.x) | (o.y ^ op.y) | (o.z ^ op.z) | (o.w ^ op.w);
        ((unsigned char*)&cbuf[nx])[wv] = ch ? 1u : 0u;
        op = o;
        if (xrow) ((uint4*)(xrow + (size_t)t * 32))[wv] = o;
      }
      __syncthreads();  // order this step's writes before next step's reads
      pb = nx;
    }
    cur = nxt;
  }
  if (lane == 0) {  // h(511) = op
    hidm[b * 32 + 2 * wv] = ((unsigned long long)op.y << 32) | op.x;
    hidm[b * 32 + 2 * wv + 1] = ((unsigned long long)op.w << 32) | op.z;
  }
}

__global__ __launch_bounds__(64) void k_fc(const unsigned long long* __restrict__ hidm,
    const unsigned long long* __restrict__ fcm, const int* __restrict__ flags,
    void* __restrict__ out) {
  int isf32 = flags[0];
  int lb = blockIdx.x, lane = threadIdx.x;
  unsigned long long hp = 0, hz = 0;
  if (lane < 16) {
    hp = hidm[lb * 32 + 2 * lane];
    hz = hidm[lb * 32 + 2 * lane + 1];
  }
#pragma unroll
  for (int o = 0; o < 4; o++) {
    int k = 0;
    if (lane < 16) {
      unsigned long long wp = fcm[o * 32 + 2 * lane], wz = fcm[o * 32 + 2 * lane + 1];
      unsigned long long both = hz & wz;
      unsigned long long neg = both & (hp ^ wp);
      k = __popcll(both) - 2 * __popcll(neg);
    }
    for (int off = 8; off > 0; off >>= 1) k += __shfl_down(k, off);
    if (lane == 0) {
      float v = (float)((double)k * 0.1);
      if (isf32) ((float*)out)[lb * 4 + o] = v;
      else       ((unsigned short*)out)[lb * 4 + o] = f2bf(v);
    }
  }
}

extern "C" void kernel_launch(void* const* d_in, const int* in_sizes, int n_in,
                              void* d_out, int out_size, void* d_ws, size_t ws_size,
                              hipStream_t stream) {
  (void)in_sizes; (void)n_in; (void)out_size; (void)ws_size;
  const int* text = (const int*)d_in[0];
  // d_in[1] text_lengths: unused by the reference
  const void* emb = d_in[2];
  const void* Wih = d_in[3];
  const void* Whh = d_in[4];
  const void* bih = d_in[5];
  const void* bhh = d_in[6];
  const void* fcw = d_in[7];

  // workspace layout (~73 MB)
  char* ws = (char*)d_ws;
  size_t off = 0;
  int* flags = (int*)(ws);
  unsigned* mab = (unsigned*)(ws + 64);                      off += 256;
  unsigned long long* x0 = (unsigned long long*)(ws + off);  off += (size_t)32768 * 256;
  unsigned long long* wim = (unsigned long long*)(ws + off); off += (size_t)2048 * 256;
  unsigned long long* whm = (unsigned long long*)(ws + off); off += (size_t)2048 * 256;
  unsigned long long* fcm = (unsigned long long*)(ws + off); off += (size_t)4 * 256;
  unsigned long long* hidm = (unsigned long long*)(ws + off); off += (size_t)128 * 256;
  short* nbufT = (short*)(ws + off);                         off += (size_t)32768 * 1024 * 2;

  hipMemsetAsync(ws, 0, 256, stream);
  k_detect<<<256, 256, 0, stream>>>((const unsigned short*)emb, text, flags);
  k_maxabs<<<2048, 256, 0, stream>>>((const uint4*)emb, flags, mab);
  k_tern_rows<<<4100, 1024, 0, stream>>>(Wih, Whh, fcw, flags, wim, whm, fcm);
  k_embed<<<32768, 1024, 0, stream>>>(text, emb, flags, mab, x0);
  // layer 0: x0 -> nbufT -> recurrence -> x0 (x0 dead after bitgemm)
  k_bitgemm<<<dim3(512, 4), 256, 0, stream>>>(x0, wim, nbufT);
  k_recur<<<64, 1024, 0, stream>>>(nbufT, whm, bih, bhh, flags, 0, x0, hidm);
  // layer 1
  k_bitgemm<<<dim3(512, 4), 256, 0, stream>>>(x0, wim + (size_t)1024 * 32, nbufT);
  k_recur<<<64, 1024, 0, stream>>>(nbufT, whm + (size_t)1024 * 32, bih, bhh, flags, 1,
                                   (unsigned long long*)0, hidm + 64 * 32);
  k_fc<<<128, 64, 0, stream>>>(hidm, fcm, flags, d_out);
}